// Round 3
// baseline (97483.447 us; speedup 1.0000x reference)
//
#include <hip/hip_runtime.h>
#include <hip/hip_bf16.h>

// MPNN: h = lin_in(x); 4x { edge MLP(129->64->64, BN+relu) -> segment_sum(dst)
//       -> node MLP(128->64->64, BN+relu) -> residual }; out = h @ pred_W + b.
// ALL float tensors are FP32 (per reference dtypes); edge_index int32.
// Round-2 postmortem: reading fp32 inputs as bf16 caused NaN. Structure kept:
// low-memory recompute pipeline (~58 MB d_ws), CSR(dst)-sorted edges, BN
// two-pass via recompute, LDS segmented aggregation.

#define BN_EPS 1e-5f

// ---- generic helpers -------------------------------------------------------

template <int K>
__device__ __forceinline__ void fma_chunk(float* acc, const float* m,
                                          const float* __restrict__ W) {
  // W: K rows x 64 cols fp32; wave-uniform address -> scalar loads
#pragma unroll
  for (int k = 0; k < K; ++k) {
    float mv = m[k];
#pragma unroll
    for (int o = 0; o < 64; ++o) acc[o] += mv * W[k * 64 + o];
  }
}

__device__ __forceinline__ void wave_stats(const float* acc,
                                           float* __restrict__ stat, int lane) {
#pragma unroll
  for (int o = 0; o < 64; ++o) {
    float v = acc[o], q = v * v;
#pragma unroll
    for (int off = 32; off; off >>= 1) {
      v += __shfl_down(v, off, 64);
      q += __shfl_down(q, off, 64);
    }
    if (lane == 0) {
      atomicAdd(&stat[o], v);
      atomicAdd(&stat[64 + o], q);
    }
  }
}

// acc[64] = b + W^T [h_dst, h_src, ea]; returns dst (-1 if idx >= E).
__device__ __forceinline__ int edge_row1(const int* __restrict__ ei,
                                         const int* __restrict__ sorted,
                                         const float* __restrict__ ea,
                                         const float* __restrict__ h,
                                         const float* __restrict__ W,
                                         const float* __restrict__ b, int idx,
                                         int E, float* acc) {
  bool valid = idx < E;
  int e = valid ? sorted[idx] : 0;
  int vd = ei[E + e], vs = ei[e];
  const float* hd = h + (size_t)vd * 64;
  const float* hs = h + (size_t)vs * 64;
#pragma unroll
  for (int o = 0; o < 64; ++o) acc[o] = b[o];
  float m[32];
#pragma unroll
  for (int k = 0; k < 32; ++k) m[k] = hd[k];
  fma_chunk<32>(acc, m, W + 0 * 64);
#pragma unroll
  for (int k = 0; k < 32; ++k) m[k] = hd[32 + k];
  fma_chunk<32>(acc, m, W + 32 * 64);
#pragma unroll
  for (int k = 0; k < 32; ++k) m[k] = hs[k];
  fma_chunk<32>(acc, m, W + 64 * 64);
#pragma unroll
  for (int k = 0; k < 32; ++k) m[k] = hs[32 + k];
  fma_chunk<32>(acc, m, W + 96 * 64);
  float eav = ea[e];
#pragma unroll
  for (int o = 0; o < 64; ++o) acc[o] += eav * W[128 * 64 + o];
  if (!valid) {
#pragma unroll
    for (int o = 0; o < 64; ++o) acc[o] = 0.f;
  }
  return valid ? vd : -1;
}

// ---- setup kernels ---------------------------------------------------------

__global__ void lin_in_kernel(const float* __restrict__ x,
                              const float* __restrict__ W,
                              const float* __restrict__ b,
                              float* __restrict__ h, int N) {
  int gid = blockIdx.x * blockDim.x + threadIdx.x;
  if (gid >= N * 64) return;
  int n = gid >> 6, o = gid & 63;
  float acc = b[o];
#pragma unroll
  for (int k = 0; k < 6; ++k) acc += x[n * 6 + k] * W[k * 64 + o];
  h[gid] = acc;
}

__global__ void deg_kernel(const int* __restrict__ ei, int* __restrict__ deg,
                           int E) {
  int gid = blockIdx.x * blockDim.x + threadIdx.x;
  if (gid < E) atomicAdd(&deg[ei[E + gid]], 1);  // row 1 = dst
}

__global__ void scan_kernel(const int* __restrict__ deg, int* __restrict__ offs,
                            int N) {
  __shared__ int s[1024];
  int t = threadIdx.x;
  int chunk = (N + 1023) >> 10;
  int lo = t * chunk, hi = lo + chunk;
  if (hi > N) hi = N;
  if (lo > N) lo = N;
  int tot = 0;
  for (int i = lo; i < hi; ++i) tot += deg[i];
  s[t] = tot;
  __syncthreads();
  for (int off = 1; off < 1024; off <<= 1) {
    int v = (t >= off) ? s[t - off] : 0;
    __syncthreads();
    s[t] += v;
    __syncthreads();
  }
  int run = s[t] - tot;  // exclusive prefix
  for (int i = lo; i < hi; ++i) {
    offs[i] = run;
    run += deg[i];
  }
}

__global__ void fill_kernel(const int* __restrict__ ei,
                            const int* __restrict__ offs, int* __restrict__ cnt,
                            int* __restrict__ sorted, int E) {
  int gid = blockIdx.x * blockDim.x + threadIdx.x;
  if (gid >= E) return;
  int d = ei[E + gid];
  int pos = offs[d] + atomicAdd(&cnt[d], 1);
  sorted[pos] = gid;
}

__global__ void bn_finalize_kernel(const float* __restrict__ stat,
                                   const float* __restrict__ gamma,
                                   const float* __restrict__ beta, float cnt,
                                   float* __restrict__ ac) {
  int o = threadIdx.x;  // 64 threads
  float mu = stat[o] / cnt;
  float var = stat[64 + o] / cnt - mu * mu;
  var = fmaxf(var, 0.f);
  float r = rsqrtf(var + BN_EPS);
  float g = gamma[o];
  ac[o] = g * r;
  ac[64 + o] = beta[o] - mu * g * r;
}

// ---- edge pipeline (no activation storage) ---------------------------------

__global__ __launch_bounds__(256) void edge_stats1_kernel(
    const int* __restrict__ ei, const int* __restrict__ sorted,
    const float* __restrict__ ea, const float* __restrict__ h,
    const float* __restrict__ W1, const float* __restrict__ b1,
    float* __restrict__ stat, int E) {
  int idx = blockIdx.x * 256 + threadIdx.x;
  float acc[64];
  edge_row1(ei, sorted, ea, h, W1, b1, idx, E, acc);
  wave_stats(acc, stat, threadIdx.x & 63);
}

__global__ __launch_bounds__(256) void edge_stats2_kernel(
    const int* __restrict__ ei, const int* __restrict__ sorted,
    const float* __restrict__ ea, const float* __restrict__ h,
    const float* __restrict__ W1, const float* __restrict__ b1,
    const float* __restrict__ ac1, const float* __restrict__ W2,
    const float* __restrict__ b2, float* __restrict__ stat, int E) {
  int idx = blockIdx.x * 256 + threadIdx.x;
  bool valid = idx < E;
  float acc[64];
  edge_row1(ei, sorted, ea, h, W1, b1, idx, E, acc);
#pragma unroll
  for (int k = 0; k < 64; ++k)
    acc[k] = fmaxf(acc[k] * ac1[k] + ac1[64 + k], 0.f);
  float acc2[64];
#pragma unroll
  for (int o = 0; o < 64; ++o) acc2[o] = b2[o];
  fma_chunk<64>(acc2, acc, W2);
  if (!valid) {
#pragma unroll
    for (int o = 0; o < 64; ++o) acc2[o] = 0.f;
  }
  wave_stats(acc2, stat, threadIdx.x & 63);
}

__global__ __launch_bounds__(128) void edge_aggr_kernel(
    const int* __restrict__ ei, const int* __restrict__ sorted,
    const float* __restrict__ ea, const float* __restrict__ h,
    const float* __restrict__ W1, const float* __restrict__ b1,
    const float* __restrict__ ac1, const float* __restrict__ W2,
    const float* __restrict__ b2, const float* __restrict__ ac2,
    float* __restrict__ aggr, int E) {
  __shared__ float srow[128 * 65];  // stride 65: conflict-free both phases
  __shared__ int sdst[128];
  int t = threadIdx.x;
  int idx = blockIdx.x * 128 + t;
  bool valid = idx < E;
  float acc[64];
  int dst = edge_row1(ei, sorted, ea, h, W1, b1, idx, E, acc);
#pragma unroll
  for (int k = 0; k < 64; ++k)
    acc[k] = fmaxf(acc[k] * ac1[k] + ac1[64 + k], 0.f);
  float acc2[64];
#pragma unroll
  for (int o = 0; o < 64; ++o) acc2[o] = b2[o];
  fma_chunk<64>(acc2, acc, W2);
#pragma unroll
  for (int o = 0; o < 64; ++o) {
    float v = fmaxf(acc2[o] * ac2[o] + ac2[64 + o], 0.f);
    srow[t * 65 + o] = valid ? v : 0.f;
  }
  sdst[t] = dst;  // -1 when invalid
  __syncthreads();
  // segmented sum over dst-sorted runs: thread (g,o) scans 64 rows, flushes
  // one coalesced atomicAdd per run boundary (partials across blocks OK).
  int o = t & 63, g = t >> 6;
  int r0 = g * 64;
  float s = 0.f;
  for (int r = r0; r < r0 + 64; ++r) {
    int d = sdst[r];
    s += srow[r * 65 + o];
    int dn = (r == r0 + 63) ? -2 : sdst[r + 1];  // force flush at window end
    if (d != dn) {
      if (d >= 0) atomicAdd(&aggr[(size_t)d * 64 + o], s);
      s = 0.f;
    }
  }
}

// ---- node pipeline ---------------------------------------------------------

__global__ __launch_bounds__(256) void node_gemm1_kernel(
    const float* __restrict__ h, const float* __restrict__ aggr,
    const float* __restrict__ W, const float* __restrict__ b,
    float* __restrict__ u1, float* __restrict__ stat, int N) {
  int idx = blockIdx.x * 256 + threadIdx.x;
  bool valid = idx < N;
  int n = valid ? idx : 0;
  float acc[64];
#pragma unroll
  for (int o = 0; o < 64; ++o) acc[o] = b[o];
  const float* hr = h + (size_t)n * 64;
  const float* ar = aggr + (size_t)n * 64;
  float m[32];
#pragma unroll
  for (int k = 0; k < 32; ++k) m[k] = hr[k];
  fma_chunk<32>(acc, m, W + 0 * 64);
#pragma unroll
  for (int k = 0; k < 32; ++k) m[k] = hr[32 + k];
  fma_chunk<32>(acc, m, W + 32 * 64);
#pragma unroll
  for (int k = 0; k < 32; ++k) m[k] = ar[k];
  fma_chunk<32>(acc, m, W + 64 * 64);
#pragma unroll
  for (int k = 0; k < 32; ++k) m[k] = ar[32 + k];
  fma_chunk<32>(acc, m, W + 96 * 64);
  if (!valid) {
#pragma unroll
    for (int o = 0; o < 64; ++o) acc[o] = 0.f;
  }
  wave_stats(acc, stat, threadIdx.x & 63);
  if (valid) {
    float* ur = u1 + (size_t)idx * 64;
#pragma unroll
    for (int o = 0; o < 64; ++o) ur[o] = acc[o];
  }
}

__global__ __launch_bounds__(256) void node_gemm2_kernel(
    const float* __restrict__ u1, const float* __restrict__ ac,
    const float* __restrict__ W, const float* __restrict__ b,
    float* __restrict__ u2, float* __restrict__ stat, int N) {
  int idx = blockIdx.x * 256 + threadIdx.x;
  bool valid = idx < N;
  float z[64];
  if (valid) {
    const float* ur = u1 + (size_t)idx * 64;
#pragma unroll
    for (int k = 0; k < 64; ++k) z[k] = fmaxf(ur[k] * ac[k] + ac[64 + k], 0.f);
  } else {
#pragma unroll
    for (int k = 0; k < 64; ++k) z[k] = 0.f;
  }
  float acc[64];
#pragma unroll
  for (int o = 0; o < 64; ++o) acc[o] = b[o];
  fma_chunk<64>(acc, z, W);
  if (!valid) {
#pragma unroll
    for (int o = 0; o < 64; ++o) acc[o] = 0.f;
  }
  wave_stats(acc, stat, threadIdx.x & 63);
  if (valid) {
    float* ur = u2 + (size_t)idx * 64;
#pragma unroll
    for (int o = 0; o < 64; ++o) ur[o] = acc[o];
  }
}

__global__ void residual_kernel(float* __restrict__ h,
                                const float* __restrict__ u2,
                                const float* __restrict__ ac, int total) {
  int gid = blockIdx.x * blockDim.x + threadIdx.x;
  if (gid >= total) return;
  int o = gid & 63;
  float v = u2[gid] * ac[o] + ac[64 + o];
  h[gid] += fmaxf(v, 0.f);
}

__global__ void pred_kernel(const float* __restrict__ h,
                            const float* __restrict__ W,
                            const float* __restrict__ b,
                            float* __restrict__ out, int N) {
  int n = blockIdx.x * blockDim.x + threadIdx.x;
  if (n >= N) return;
  float acc = b[0];
  const float* hr = h + (size_t)n * 64;
#pragma unroll
  for (int o = 0; o < 64; ++o) acc += hr[o] * W[o];
  out[n] = acc;
}

// ---- launch ----------------------------------------------------------------

extern "C" void kernel_launch(void* const* d_in, const int* in_sizes, int n_in,
                              void* d_out, int out_size, void* d_ws,
                              size_t ws_size, hipStream_t stream) {
  const float* x = (const float*)d_in[0];
  const int* ei = (const int*)d_in[1];
  const float* ea = (const float*)d_in[2];
  const float* lin_W = (const float*)d_in[3];
  const float* lin_b = (const float*)d_in[4];
  const float* msg_W1 = (const float*)d_in[5];
  const float* msg_b1 = (const float*)d_in[6];
  const float* msg_g1 = (const float*)d_in[7];
  const float* msg_be1 = (const float*)d_in[8];
  const float* msg_W2 = (const float*)d_in[9];
  const float* msg_b2 = (const float*)d_in[10];
  const float* msg_g2 = (const float*)d_in[11];
  const float* msg_be2 = (const float*)d_in[12];
  const float* upd_W1 = (const float*)d_in[13];
  const float* upd_b1 = (const float*)d_in[14];
  const float* upd_g1 = (const float*)d_in[15];
  const float* upd_be1 = (const float*)d_in[16];
  const float* upd_W2 = (const float*)d_in[17];
  const float* upd_b2 = (const float*)d_in[18];
  const float* upd_g2 = (const float*)d_in[19];
  const float* upd_be2 = (const float*)d_in[20];
  const float* pred_W = (const float*)d_in[21];
  const float* pred_b = (const float*)d_in[22];
  float* out = (float*)d_out;

  const int N = in_sizes[0] / 6;
  const int E = in_sizes[1] / 2;
  const int L = 4;

  // workspace carve: ~58 MB total
  char* p = (char*)d_ws;
  auto alloc = [&](size_t bytes) {
    void* r = (void*)p;
    p += (bytes + 255) & ~(size_t)255;
    return r;
  };
  float* h = (float*)alloc((size_t)N * 64 * 4);     // 12.8 MB
  float* aggr = (float*)alloc((size_t)N * 64 * 4);  // 12.8 MB
  float* u1 = (float*)alloc((size_t)N * 64 * 4);    // 12.8 MB
  float* u2 = (float*)alloc((size_t)N * 64 * 4);    // 12.8 MB
  float* stats = (float*)alloc(512 * 4);
  float* ac1 = (float*)alloc(128 * 4);
  float* ac2 = (float*)alloc(128 * 4);
  float* acu1 = (float*)alloc(128 * 4);
  float* acu2 = (float*)alloc(128 * 4);
  int* deg = (int*)alloc((size_t)N * 4);
  int* offs = (int*)alloc((size_t)N * 4);
  int* cnt = (int*)alloc((size_t)N * 4);
  int* sorted = (int*)alloc((size_t)E * 4);  // 6.4 MB

  const int B = 256;
  int gridE256 = (E + 255) / 256;
  int gridE128 = (E + 127) / 128;
  int gridN64 = (N * 64 + B - 1) / B;
  int gridN = (N + B - 1) / B;

  // setup
  hipMemsetAsync(deg, 0, (size_t)N * 4, stream);
  hipMemsetAsync(cnt, 0, (size_t)N * 4, stream);
  lin_in_kernel<<<gridN64, B, 0, stream>>>(x, lin_W, lin_b, h, N);
  deg_kernel<<<gridE256, B, 0, stream>>>(ei, deg, E);
  scan_kernel<<<1, 1024, 0, stream>>>(deg, offs, N);
  fill_kernel<<<gridE256, B, 0, stream>>>(ei, offs, cnt, sorted, E);

  for (int l = 0; l < L; ++l) {
    const float* W1 = msg_W1 + (size_t)l * 129 * 64;
    const float* W2 = msg_W2 + (size_t)l * 64 * 64;
    const float* U1 = upd_W1 + (size_t)l * 128 * 64;
    const float* U2 = upd_W2 + (size_t)l * 64 * 64;
    hipMemsetAsync(stats, 0, 512 * 4, stream);
    hipMemsetAsync(aggr, 0, (size_t)N * 64 * 4, stream);
    edge_stats1_kernel<<<gridE256, 256, 0, stream>>>(ei, sorted, ea, h, W1,
                                                     msg_b1 + l * 64, stats, E);
    bn_finalize_kernel<<<1, 64, 0, stream>>>(stats, msg_g1 + l * 64,
                                             msg_be1 + l * 64, (float)E, ac1);
    edge_stats2_kernel<<<gridE256, 256, 0, stream>>>(
        ei, sorted, ea, h, W1, msg_b1 + l * 64, ac1, W2, msg_b2 + l * 64,
        stats + 128, E);
    bn_finalize_kernel<<<1, 64, 0, stream>>>(stats + 128, msg_g2 + l * 64,
                                             msg_be2 + l * 64, (float)E, ac2);
    edge_aggr_kernel<<<gridE128, 128, 0, stream>>>(
        ei, sorted, ea, h, W1, msg_b1 + l * 64, ac1, W2, msg_b2 + l * 64, ac2,
        aggr, E);
    node_gemm1_kernel<<<gridN, 256, 0, stream>>>(h, aggr, U1, upd_b1 + l * 64,
                                                 u1, stats + 256, N);
    bn_finalize_kernel<<<1, 64, 0, stream>>>(stats + 256, upd_g1 + l * 64,
                                             upd_be1 + l * 64, (float)N, acu1);
    node_gemm2_kernel<<<gridN, 256, 0, stream>>>(u1, acu1, U2, upd_b2 + l * 64,
                                                 u2, stats + 384, N);
    bn_finalize_kernel<<<1, 64, 0, stream>>>(stats + 384, upd_g2 + l * 64,
                                             upd_be2 + l * 64, (float)N, acu2);
    residual_kernel<<<gridN64, B, 0, stream>>>(h, u2, acu2, N * 64);
  }
  pred_kernel<<<gridN, B, 0, stream>>>(h, pred_W, pred_b, out, N);
}

// Round 4
// 23939.821 us; speedup vs baseline: 4.0720x; 4.0720x over previous
//
#include <hip/hip_runtime.h>
#include <hip/hip_bf16.h>

// MPNN: h = lin_in(x); 4x { edge MLP(129->64->64, BN+relu) -> segment_sum(dst)
//       -> node MLP(128->64->64, BN+relu) -> residual }; out = h @ pred_W + b.
// FP32 tensors, int32 edge_index. Round-3 postmortem: thread-per-edge acc[64]
// spilled to scratch (VGPR=68, VALUBusy 3%, FETCH 478MB). Rewrite: LDS-tiled
// GEMM, block = 64 rows x 64 cols, thread = 4x4 register tile (16 VGPRs).
// BN two-pass via recompute (3 edge passes); dst-sorted CSR + LDS segmented
// aggregation. ~58 MB d_ws.

#define BN_EPS 1e-5f
#define ASW 68  // LDS A-tile row stride in words (16B-aligned, conflict-free)

// ---- small setup kernels (unchanged from round 3) --------------------------

__global__ void lin_in_kernel(const float* __restrict__ x,
                              const float* __restrict__ W,
                              const float* __restrict__ b,
                              float* __restrict__ h, int N) {
  int gid = blockIdx.x * blockDim.x + threadIdx.x;
  if (gid >= N * 64) return;
  int n = gid >> 6, o = gid & 63;
  float acc = b[o];
#pragma unroll
  for (int k = 0; k < 6; ++k) acc += x[n * 6 + k] * W[k * 64 + o];
  h[gid] = acc;
}

__global__ void deg_kernel(const int* __restrict__ ei, int* __restrict__ deg,
                           int E) {
  int gid = blockIdx.x * blockDim.x + threadIdx.x;
  if (gid < E) atomicAdd(&deg[ei[E + gid]], 1);  // row 1 = dst
}

__global__ void scan_kernel(const int* __restrict__ deg, int* __restrict__ offs,
                            int N) {
  __shared__ int s[1024];
  int t = threadIdx.x;
  int chunk = (N + 1023) >> 10;
  int lo = t * chunk, hi = lo + chunk;
  if (hi > N) hi = N;
  if (lo > N) lo = N;
  int tot = 0;
  for (int i = lo; i < hi; ++i) tot += deg[i];
  s[t] = tot;
  __syncthreads();
  for (int off = 1; off < 1024; off <<= 1) {
    int v = (t >= off) ? s[t - off] : 0;
    __syncthreads();
    s[t] += v;
    __syncthreads();
  }
  int run = s[t] - tot;  // exclusive prefix
  for (int i = lo; i < hi; ++i) {
    offs[i] = run;
    run += deg[i];
  }
}

__global__ void fill_kernel(const int* __restrict__ ei,
                            const int* __restrict__ offs, int* __restrict__ cnt,
                            int* __restrict__ sorted, int E) {
  int gid = blockIdx.x * blockDim.x + threadIdx.x;
  if (gid >= E) return;
  int d = ei[E + gid];
  int pos = offs[d] + atomicAdd(&cnt[d], 1);
  sorted[pos] = gid;
}

__global__ void bn_finalize_kernel(const float* __restrict__ stat,
                                   const float* __restrict__ gamma,
                                   const float* __restrict__ beta, float cnt,
                                   float* __restrict__ ac) {
  int o = threadIdx.x;  // 64 threads
  float mu = stat[o] / cnt;
  float var = stat[64 + o] / cnt - mu * mu;
  var = fmaxf(var, 0.f);
  float r = rsqrtf(var + BN_EPS);
  float g = gamma[o];
  ac[o] = g * r;
  ac[64 + o] = beta[o] - mu * g * r;
}

// ---- tiled-GEMM building blocks --------------------------------------------
// Block: 256 threads. tx = t&15 (row quad), ty = t>>4 (col quad).
// Thread computes acc[4][4] for rows tx*4..+3, cols ty*4..+3.

__device__ __forceinline__ void gemm_tile(const float* __restrict__ As,
                                          const float* __restrict__ W, int K,
                                          int tx, int ty, float acc[4][4]) {
#pragma unroll 8
  for (int k = 0; k < K; ++k) {
    float4 a = *(const float4*)&As[k * ASW + tx * 4];
    float4 w = *(const float4*)&W[k * 64 + ty * 4];
    float av[4] = {a.x, a.y, a.z, a.w};
    float wv[4] = {w.x, w.y, w.z, w.w};
#pragma unroll
    for (int i = 0; i < 4; ++i)
#pragma unroll
      for (int j = 0; j < 4; ++j) acc[i][j] += av[i] * wv[j];
  }
}

// column sums & sumsq across the block's 64 rows -> atomics into stat[128]
__device__ __forceinline__ void stats_tile(const float acc[4][4],
                                           float* __restrict__ stat, int tx,
                                           int ty) {
  float s[4], q[4];
#pragma unroll
  for (int j = 0; j < 4; ++j) {
    s[j] = 0.f;
    q[j] = 0.f;
#pragma unroll
    for (int i = 0; i < 4; ++i) {
      s[j] += acc[i][j];
      q[j] += acc[i][j] * acc[i][j];
    }
  }
#pragma unroll
  for (int off = 8; off; off >>= 1) {
#pragma unroll
    for (int j = 0; j < 4; ++j) {
      s[j] += __shfl_down(s[j], off, 16);
      q[j] += __shfl_down(q[j], off, 16);
    }
  }
  if (tx == 0) {
#pragma unroll
    for (int j = 0; j < 4; ++j) {
      atomicAdd(&stat[ty * 4 + j], s[j]);
      atomicAdd(&stat[64 + ty * 4 + j], q[j]);
    }
  }
}

// stage A = [h_dst | h_src | ea] for 64 dst-sorted edges into As[k][e]
__device__ __forceinline__ void stage_edges(const int* __restrict__ ei,
                                            const int* __restrict__ sorted,
                                            const float* __restrict__ ea,
                                            const float* __restrict__ h, int E,
                                            int idx0, float* __restrict__ As,
                                            int* __restrict__ sdst,
                                            int* __restrict__ ssrc) {
  int t = threadIdx.x;
  if (t < 64) {
    int idx = idx0 + t;
    bool v = idx < E;
    int sid = v ? sorted[idx] : 0;
    sdst[t] = v ? ei[E + sid] : -1;
    ssrc[t] = v ? ei[sid] : 0;
    As[128 * ASW + t] = v ? ea[sid] : 0.f;
  }
  __syncthreads();
  int c = t & 63, g = t >> 6;  // wave g handles edges g, g+4, ... lanes = c
  for (int e = g; e < 64; e += 4) {
    int d = sdst[e], sidx = ssrc[e];
    bool v = d >= 0;
    As[c * ASW + e] = v ? h[(size_t)d * 64 + c] : 0.f;
    As[(64 + c) * ASW + e] = v ? h[(size_t)sidx * 64 + c] : 0.f;
  }
  __syncthreads();
}

// ---- edge pipeline ---------------------------------------------------------

__global__ __launch_bounds__(256) void edge_stats1_v2(
    const int* __restrict__ ei, const int* __restrict__ sorted,
    const float* __restrict__ ea, const float* __restrict__ h,
    const float* __restrict__ W1, const float* __restrict__ b1,
    float* __restrict__ stat, int E) {
  __shared__ __align__(16) float As[129 * ASW];
  __shared__ int sdst[64], ssrc[64];
  int idx0 = blockIdx.x * 64;
  stage_edges(ei, sorted, ea, h, E, idx0, As, sdst, ssrc);
  int t = threadIdx.x, tx = t & 15, ty = t >> 4;
  float acc[4][4];
#pragma unroll
  for (int i = 0; i < 4; ++i)
#pragma unroll
    for (int j = 0; j < 4; ++j) acc[i][j] = b1[ty * 4 + j];
  gemm_tile(As, W1, 129, tx, ty, acc);
#pragma unroll
  for (int i = 0; i < 4; ++i)
    if (sdst[tx * 4 + i] < 0) {
#pragma unroll
      for (int j = 0; j < 4; ++j) acc[i][j] = 0.f;
    }
  stats_tile(acc, stat, tx, ty);
}

__global__ __launch_bounds__(256) void edge_stats2_v2(
    const int* __restrict__ ei, const int* __restrict__ sorted,
    const float* __restrict__ ea, const float* __restrict__ h,
    const float* __restrict__ W1, const float* __restrict__ b1,
    const float* __restrict__ ac1, const float* __restrict__ W2,
    const float* __restrict__ b2, float* __restrict__ stat, int E) {
  __shared__ __align__(16) float As[129 * ASW];
  __shared__ int sdst[64], ssrc[64];
  int idx0 = blockIdx.x * 64;
  stage_edges(ei, sorted, ea, h, E, idx0, As, sdst, ssrc);
  int t = threadIdx.x, tx = t & 15, ty = t >> 4;
  float acc[4][4];
#pragma unroll
  for (int i = 0; i < 4; ++i)
#pragma unroll
    for (int j = 0; j < 4; ++j) acc[i][j] = b1[ty * 4 + j];
  gemm_tile(As, W1, 129, tx, ty, acc);
  __syncthreads();  // all GEMM1 reads of As done
  // BN1 + relu, re-stage as Zs[k=col][e] overlaying As rows 0..63
#pragma unroll
  for (int j = 0; j < 4; ++j) {
    int cj = ty * 4 + j;
    float a1 = ac1[cj], c1 = ac1[64 + cj];
#pragma unroll
    for (int i = 0; i < 4; ++i)
      As[cj * ASW + tx * 4 + i] = fmaxf(acc[i][j] * a1 + c1, 0.f);
  }
  __syncthreads();
  float acc2[4][4];
#pragma unroll
  for (int i = 0; i < 4; ++i)
#pragma unroll
    for (int j = 0; j < 4; ++j) acc2[i][j] = b2[ty * 4 + j];
  gemm_tile(As, W2, 64, tx, ty, acc2);
#pragma unroll
  for (int i = 0; i < 4; ++i)
    if (sdst[tx * 4 + i] < 0) {
#pragma unroll
      for (int j = 0; j < 4; ++j) acc2[i][j] = 0.f;
    }
  stats_tile(acc2, stat, tx, ty);
}

__global__ __launch_bounds__(256) void edge_aggr_v2(
    const int* __restrict__ ei, const int* __restrict__ sorted,
    const float* __restrict__ ea, const float* __restrict__ h,
    const float* __restrict__ W1, const float* __restrict__ b1,
    const float* __restrict__ ac1, const float* __restrict__ W2,
    const float* __restrict__ b2, const float* __restrict__ ac2,
    float* __restrict__ aggr, int E) {
  __shared__ __align__(16) float As[129 * ASW];
  __shared__ int sdst[64], ssrc[64];
  int idx0 = blockIdx.x * 64;
  stage_edges(ei, sorted, ea, h, E, idx0, As, sdst, ssrc);
  int t = threadIdx.x, tx = t & 15, ty = t >> 4;
  float acc[4][4];
#pragma unroll
  for (int i = 0; i < 4; ++i)
#pragma unroll
    for (int j = 0; j < 4; ++j) acc[i][j] = b1[ty * 4 + j];
  gemm_tile(As, W1, 129, tx, ty, acc);
  __syncthreads();
#pragma unroll
  for (int j = 0; j < 4; ++j) {
    int cj = ty * 4 + j;
    float a1 = ac1[cj], c1 = ac1[64 + cj];
#pragma unroll
    for (int i = 0; i < 4; ++i)
      As[cj * ASW + tx * 4 + i] = fmaxf(acc[i][j] * a1 + c1, 0.f);
  }
  __syncthreads();
  float acc2[4][4];
#pragma unroll
  for (int i = 0; i < 4; ++i)
#pragma unroll
    for (int j = 0; j < 4; ++j) acc2[i][j] = b2[ty * 4 + j];
  gemm_tile(As, W2, 64, tx, ty, acc2);
  // BN2 + relu -> Ys[e][c] in As rows 64..128 (disjoint from Zs rows 0..63)
  float* Ys = As + 64 * ASW;
#pragma unroll
  for (int j = 0; j < 4; ++j) {
    int cj = ty * 4 + j;
    float a2 = ac2[cj], c2 = ac2[64 + cj];
#pragma unroll
    for (int i = 0; i < 4; ++i) {
      bool v = sdst[tx * 4 + i] >= 0;
      Ys[(tx * 4 + i) * ASW + cj] = v ? fmaxf(acc2[i][j] * a2 + c2, 0.f) : 0.f;
    }
  }
  __syncthreads();
  // segmented sum over dst-sorted runs (partials across blocks OK via atomics)
  int col = t & 63, g = t >> 6;
  float s = 0.f;
  for (int e = g * 16; e < g * 16 + 16; ++e) {
    int d = sdst[e];
    s += Ys[e * ASW + col];
    int dn = (e == g * 16 + 15) ? -2 : sdst[e + 1];
    if (d != dn) {
      if (d >= 0) atomicAdd(&aggr[(size_t)d * 64 + col], s);
      s = 0.f;
    }
  }
}

// ---- node pipeline ---------------------------------------------------------

__global__ __launch_bounds__(256) void node_gemm1_v2(
    const float* __restrict__ h, const float* __restrict__ aggr,
    const float* __restrict__ W, const float* __restrict__ b,
    float* __restrict__ u1, float* __restrict__ stat, int N) {
  __shared__ __align__(16) float As[128 * ASW];
  int n0 = blockIdx.x * 64;
  int t = threadIdx.x;
  int c = t & 63, g = t >> 6;
  for (int n = g; n < 64; n += 4) {
    int idx = n0 + n;
    bool v = idx < N;
    As[c * ASW + n] = v ? h[(size_t)idx * 64 + c] : 0.f;
    As[(64 + c) * ASW + n] = v ? aggr[(size_t)idx * 64 + c] : 0.f;
  }
  __syncthreads();
  int tx = t & 15, ty = t >> 4;
  float acc[4][4];
#pragma unroll
  for (int i = 0; i < 4; ++i)
#pragma unroll
    for (int j = 0; j < 4; ++j) acc[i][j] = b[ty * 4 + j];
  gemm_tile(As, W, 128, tx, ty, acc);
#pragma unroll
  for (int i = 0; i < 4; ++i) {
    int idx = n0 + tx * 4 + i;
    if (idx < N) {
      *(float4*)&u1[(size_t)idx * 64 + ty * 4] =
          make_float4(acc[i][0], acc[i][1], acc[i][2], acc[i][3]);
    } else {
#pragma unroll
      for (int j = 0; j < 4; ++j) acc[i][j] = 0.f;
    }
  }
  stats_tile(acc, stat, tx, ty);
}

__global__ __launch_bounds__(256) void node_gemm2_v2(
    const float* __restrict__ u1, const float* __restrict__ ac,
    const float* __restrict__ W, const float* __restrict__ b,
    float* __restrict__ u2, float* __restrict__ stat, int N) {
  __shared__ __align__(16) float As[64 * ASW];
  int n0 = blockIdx.x * 64;
  int t = threadIdx.x;
  int c = t & 63, g = t >> 6;
  float a1 = ac[c], c1 = ac[64 + c];
  for (int n = g; n < 64; n += 4) {
    int idx = n0 + n;
    bool v = idx < N;
    As[c * ASW + n] =
        v ? fmaxf(u1[(size_t)idx * 64 + c] * a1 + c1, 0.f) : 0.f;
  }
  __syncthreads();
  int tx = t & 15, ty = t >> 4;
  float acc[4][4];
#pragma unroll
  for (int i = 0; i < 4; ++i)
#pragma unroll
    for (int j = 0; j < 4; ++j) acc[i][j] = b[ty * 4 + j];
  gemm_tile(As, W, 64, tx, ty, acc);
#pragma unroll
  for (int i = 0; i < 4; ++i) {
    int idx = n0 + tx * 4 + i;
    if (idx < N) {
      *(float4*)&u2[(size_t)idx * 64 + ty * 4] =
          make_float4(acc[i][0], acc[i][1], acc[i][2], acc[i][3]);
    } else {
#pragma unroll
      for (int j = 0; j < 4; ++j) acc[i][j] = 0.f;
    }
  }
  stats_tile(acc, stat, tx, ty);
}

__global__ void residual_kernel(float* __restrict__ h,
                                const float* __restrict__ u2,
                                const float* __restrict__ ac, int total) {
  int gid = blockIdx.x * blockDim.x + threadIdx.x;
  if (gid >= total) return;
  int o = gid & 63;
  float v = u2[gid] * ac[o] + ac[64 + o];
  h[gid] += fmaxf(v, 0.f);
}

__global__ void pred_kernel(const float* __restrict__ h,
                            const float* __restrict__ W,
                            const float* __restrict__ b,
                            float* __restrict__ out, int N) {
  int n = blockIdx.x * blockDim.x + threadIdx.x;
  if (n >= N) return;
  float acc = b[0];
  const float* hr = h + (size_t)n * 64;
#pragma unroll
  for (int o = 0; o < 64; ++o) acc += hr[o] * W[o];
  out[n] = acc;
}

// ---- launch ----------------------------------------------------------------

extern "C" void kernel_launch(void* const* d_in, const int* in_sizes, int n_in,
                              void* d_out, int out_size, void* d_ws,
                              size_t ws_size, hipStream_t stream) {
  const float* x = (const float*)d_in[0];
  const int* ei = (const int*)d_in[1];
  const float* ea = (const float*)d_in[2];
  const float* lin_W = (const float*)d_in[3];
  const float* lin_b = (const float*)d_in[4];
  const float* msg_W1 = (const float*)d_in[5];
  const float* msg_b1 = (const float*)d_in[6];
  const float* msg_g1 = (const float*)d_in[7];
  const float* msg_be1 = (const float*)d_in[8];
  const float* msg_W2 = (const float*)d_in[9];
  const float* msg_b2 = (const float*)d_in[10];
  const float* msg_g2 = (const float*)d_in[11];
  const float* msg_be2 = (const float*)d_in[12];
  const float* upd_W1 = (const float*)d_in[13];
  const float* upd_b1 = (const float*)d_in[14];
  const float* upd_g1 = (const float*)d_in[15];
  const float* upd_be1 = (const float*)d_in[16];
  const float* upd_W2 = (const float*)d_in[17];
  const float* upd_b2 = (const float*)d_in[18];
  const float* upd_g2 = (const float*)d_in[19];
  const float* upd_be2 = (const float*)d_in[20];
  const float* pred_W = (const float*)d_in[21];
  const float* pred_b = (const float*)d_in[22];
  float* out = (float*)d_out;

  const int N = in_sizes[0] / 6;
  const int E = in_sizes[1] / 2;
  const int L = 4;

  // workspace carve: ~58 MB total
  char* p = (char*)d_ws;
  auto alloc = [&](size_t bytes) {
    void* r = (void*)p;
    p += (bytes + 255) & ~(size_t)255;
    return r;
  };
  float* h = (float*)alloc((size_t)N * 64 * 4);
  float* aggr = (float*)alloc((size_t)N * 64 * 4);
  float* u1 = (float*)alloc((size_t)N * 64 * 4);
  float* u2 = (float*)alloc((size_t)N * 64 * 4);
  float* stats = (float*)alloc(512 * 4);  // msg1|msg2|upd1|upd2
  float* ac1 = (float*)alloc(128 * 4);
  float* ac2 = (float*)alloc(128 * 4);
  float* acu1 = (float*)alloc(128 * 4);
  float* acu2 = (float*)alloc(128 * 4);
  int* deg = (int*)alloc((size_t)N * 4);
  int* offs = (int*)alloc((size_t)N * 4);
  int* cnt = (int*)alloc((size_t)N * 4);
  int* sorted = (int*)alloc((size_t)E * 4);

  const int B = 256;
  int gridE256 = (E + 255) / 256;
  int gridE64 = (E + 63) / 64;    // 25000
  int gridM64 = (N + 63) / 64;    // 782
  int gridN64 = (N * 64 + B - 1) / B;
  int gridN = (N + B - 1) / B;

  // setup
  hipMemsetAsync(deg, 0, (size_t)N * 4, stream);
  hipMemsetAsync(cnt, 0, (size_t)N * 4, stream);
  lin_in_kernel<<<gridN64, B, 0, stream>>>(x, lin_W, lin_b, h, N);
  deg_kernel<<<gridE256, B, 0, stream>>>(ei, deg, E);
  scan_kernel<<<1, 1024, 0, stream>>>(deg, offs, N);
  fill_kernel<<<gridE256, B, 0, stream>>>(ei, offs, cnt, sorted, E);

  for (int l = 0; l < L; ++l) {
    const float* W1 = msg_W1 + (size_t)l * 129 * 64;
    const float* W2 = msg_W2 + (size_t)l * 64 * 64;
    const float* U1 = upd_W1 + (size_t)l * 128 * 64;
    const float* U2 = upd_W2 + (size_t)l * 64 * 64;
    hipMemsetAsync(stats, 0, 512 * 4, stream);
    hipMemsetAsync(aggr, 0, (size_t)N * 64 * 4, stream);
    edge_stats1_v2<<<gridE64, 256, 0, stream>>>(ei, sorted, ea, h, W1,
                                                msg_b1 + l * 64, stats, E);
    bn_finalize_kernel<<<1, 64, 0, stream>>>(stats, msg_g1 + l * 64,
                                             msg_be1 + l * 64, (float)E, ac1);
    edge_stats2_v2<<<gridE64, 256, 0, stream>>>(
        ei, sorted, ea, h, W1, msg_b1 + l * 64, ac1, W2, msg_b2 + l * 64,
        stats + 128, E);
    bn_finalize_kernel<<<1, 64, 0, stream>>>(stats + 128, msg_g2 + l * 64,
                                             msg_be2 + l * 64, (float)E, ac2);
    edge_aggr_v2<<<gridE64, 256, 0, stream>>>(ei, sorted, ea, h, W1,
                                              msg_b1 + l * 64, ac1, W2,
                                              msg_b2 + l * 64, ac2, aggr, E);
    node_gemm1_v2<<<gridM64, 256, 0, stream>>>(h, aggr, U1, upd_b1 + l * 64,
                                               u1, stats + 256, N);
    bn_finalize_kernel<<<1, 64, 0, stream>>>(stats + 256, upd_g1 + l * 64,
                                             upd_be1 + l * 64, (float)N, acu1);
    node_gemm2_v2<<<gridM64, 256, 0, stream>>>(u1, acu1, U2, upd_b2 + l * 64,
                                               u2, stats + 384, N);
    bn_finalize_kernel<<<1, 64, 0, stream>>>(stats + 384, upd_g2 + l * 64,
                                             upd_be2 + l * 64, (float)N, acu2);
    residual_kernel<<<gridN64, B, 0, stream>>>(h, u2, acu2, N * 64);
  }
  pred_kernel<<<gridN, B, 0, stream>>>(h, pred_W, pred_b, out, N);
}

// Round 5
// 14661.224 us; speedup vs baseline: 6.6491x; 1.6329x over previous
//
#include <hip/hip_runtime.h>
#include <hip/hip_bf16.h>

// MPNN: h = lin_in(x); 4x { edge MLP(129->64->64, BN+relu) -> segment_sum(dst)
//       -> node MLP(128->64->64, BN+relu) -> residual }; out = h @ pred_W + b.
// FP32 tensors, int32 edge_index. Round-4 postmortem: BN-stats global atomics
// (3.2M ops onto 128 words per edge dispatch) serialized everything
// (VALUBusy 9-13%). Round 5: 128-way sharded stats + 2x8 register tiles
// (8 FMA per LDS word, W streamed from L1), ASW=66, 4 blocks/CU.

#define BN_EPS 1e-5f
#define ASW 66    // LDS A-tile row stride in words (even, non-pow2-ish)
#define NSH 128   // stat shards

// ---- small setup kernels ---------------------------------------------------

__global__ void lin_in_kernel(const float* __restrict__ x,
                              const float* __restrict__ W,
                              const float* __restrict__ b,
                              float* __restrict__ h, int N) {
  int gid = blockIdx.x * blockDim.x + threadIdx.x;
  if (gid >= N * 64) return;
  int n = gid >> 6, o = gid & 63;
  float acc = b[o];
#pragma unroll
  for (int k = 0; k < 6; ++k) acc += x[n * 6 + k] * W[k * 64 + o];
  h[gid] = acc;
}

__global__ void deg_kernel(const int* __restrict__ ei, int* __restrict__ deg,
                           int E) {
  int gid = blockIdx.x * blockDim.x + threadIdx.x;
  if (gid < E) atomicAdd(&deg[ei[E + gid]], 1);  // row 1 = dst
}

__global__ void scan_kernel(const int* __restrict__ deg, int* __restrict__ offs,
                            int N) {
  __shared__ int s[1024];
  int t = threadIdx.x;
  int chunk = (N + 1023) >> 10;
  int lo = t * chunk, hi = lo + chunk;
  if (hi > N) hi = N;
  if (lo > N) lo = N;
  int tot = 0;
  for (int i = lo; i < hi; ++i) tot += deg[i];
  s[t] = tot;
  __syncthreads();
  for (int off = 1; off < 1024; off <<= 1) {
    int v = (t >= off) ? s[t - off] : 0;
    __syncthreads();
    s[t] += v;
    __syncthreads();
  }
  int run = s[t] - tot;  // exclusive prefix
  for (int i = lo; i < hi; ++i) {
    offs[i] = run;
    run += deg[i];
  }
}

__global__ void fill_kernel(const int* __restrict__ ei,
                            const int* __restrict__ offs, int* __restrict__ cnt,
                            int* __restrict__ sorted, int E) {
  int gid = blockIdx.x * blockDim.x + threadIdx.x;
  if (gid >= E) return;
  int d = ei[E + gid];
  int pos = offs[d] + atomicAdd(&cnt[d], 1);
  sorted[pos] = gid;
}

// reduce NSH shards -> BN scale/shift
__global__ void bn_finalize_kernel(const float* __restrict__ shards,
                                   const float* __restrict__ gamma,
                                   const float* __restrict__ beta, float cnt,
                                   float* __restrict__ ac) {
  int o = threadIdx.x;  // 64 threads
  float s = 0.f, q = 0.f;
  for (int i = 0; i < NSH; ++i) {
    s += shards[i * 128 + o];
    q += shards[i * 128 + 64 + o];
  }
  float mu = s / cnt;
  float var = q / cnt - mu * mu;
  var = fmaxf(var, 0.f);
  float r = rsqrtf(var + BN_EPS);
  float g = gamma[o];
  ac[o] = g * r;
  ac[64 + o] = beta[o] - mu * g * r;
}

// ---- tiled-GEMM core -------------------------------------------------------
// Block 256 threads: rg = t>>3 (rows rg*2..+1), cg = t&7 (cols cg*8..+7).
// Wave covers 16 rows x 64 cols. acc[2][8] = 16 VGPRs.

__device__ __forceinline__ void gemm_r2c8(const float* __restrict__ As,
                                          const float* __restrict__ W, int K,
                                          int rg, int cg, float acc[2][8]) {
  const float* ap = As + rg * 2;
  const float* wp = W + cg * 8;
#pragma unroll 4
  for (int k = 0; k < K; ++k) {
    float2 a = *(const float2*)&ap[k * ASW];
    float4 w0 = *(const float4*)&wp[k * 64];
    float4 w1 = *(const float4*)&wp[k * 64 + 4];
    float wv[8] = {w0.x, w0.y, w0.z, w0.w, w1.x, w1.y, w1.z, w1.w};
#pragma unroll
    for (int j = 0; j < 8; ++j) {
      acc[0][j] += a.x * wv[j];
      acc[1][j] += a.y * wv[j];
    }
  }
}

// column sums/sumsq across rows -> sharded atomics (shard has 128 floats)
__device__ __forceinline__ void stats_r2c8(const float acc[2][8],
                                           float* __restrict__ shard, int t,
                                           int cg) {
  float s[8], q[8];
#pragma unroll
  for (int j = 0; j < 8; ++j) {
    s[j] = acc[0][j] + acc[1][j];
    q[j] = acc[0][j] * acc[0][j] + acc[1][j] * acc[1][j];
  }
#pragma unroll
  for (int off = 32; off >= 8; off >>= 1) {
#pragma unroll
    for (int j = 0; j < 8; ++j) {
      s[j] += __shfl_down(s[j], off, 64);
      q[j] += __shfl_down(q[j], off, 64);
    }
  }
  if (((t & 63) >> 3) == 0) {  // lanes 0..7, lane == cg
#pragma unroll
    for (int j = 0; j < 8; ++j) {
      atomicAdd(&shard[cg * 8 + j], s[j]);
      atomicAdd(&shard[64 + cg * 8 + j], q[j]);
    }
  }
}

// stage A = [h_dst | h_src | ea] for 64 dst-sorted edges into As[k][e]
__device__ __forceinline__ void stage_edges(const int* __restrict__ ei,
                                            const int* __restrict__ sorted,
                                            const float* __restrict__ ea,
                                            const float* __restrict__ h, int E,
                                            int idx0, float* __restrict__ As,
                                            int* __restrict__ sdst,
                                            int* __restrict__ ssrc) {
  int t = threadIdx.x;
  if (t < 64) {
    int idx = idx0 + t;
    bool v = idx < E;
    int sid = v ? sorted[idx] : 0;
    sdst[t] = v ? ei[E + sid] : -1;
    ssrc[t] = v ? ei[sid] : 0;
    As[128 * ASW + t] = v ? ea[sid] : 0.f;
  }
  __syncthreads();
  int c = t & 63, g = t >> 6;  // wave g handles edges g, g+4, ...; lanes = c
  for (int e = g; e < 64; e += 4) {
    int d = sdst[e], sidx = ssrc[e];
    bool v = d >= 0;
    As[c * ASW + e] = v ? h[(size_t)d * 64 + c] : 0.f;
    As[(64 + c) * ASW + e] = v ? h[(size_t)sidx * 64 + c] : 0.f;
  }
  __syncthreads();
}

__device__ __forceinline__ void zero_invalid_rows(const int* __restrict__ sdst,
                                                  int rg, float acc[2][8]) {
#pragma unroll
  for (int i = 0; i < 2; ++i)
    if (sdst[rg * 2 + i] < 0) {
#pragma unroll
      for (int j = 0; j < 8; ++j) acc[i][j] = 0.f;
    }
}

// ---- edge pipeline ---------------------------------------------------------

__global__ __launch_bounds__(256) void edge_stats1_v3(
    const int* __restrict__ ei, const int* __restrict__ sorted,
    const float* __restrict__ ea, const float* __restrict__ h,
    const float* __restrict__ W1, const float* __restrict__ b1,
    float* __restrict__ stat, int E) {
  __shared__ __align__(16) float As[129 * ASW];
  __shared__ int sdst[64], ssrc[64];
  stage_edges(ei, sorted, ea, h, E, blockIdx.x * 64, As, sdst, ssrc);
  int t = threadIdx.x, rg = t >> 3, cg = t & 7;
  float acc[2][8];
#pragma unroll
  for (int i = 0; i < 2; ++i)
#pragma unroll
    for (int j = 0; j < 8; ++j) acc[i][j] = b1[cg * 8 + j];
  gemm_r2c8(As, W1, 129, rg, cg, acc);
  zero_invalid_rows(sdst, rg, acc);
  stats_r2c8(acc, stat + (size_t)(blockIdx.x & (NSH - 1)) * 128, t, cg);
}

__global__ __launch_bounds__(256) void edge_stats2_v3(
    const int* __restrict__ ei, const int* __restrict__ sorted,
    const float* __restrict__ ea, const float* __restrict__ h,
    const float* __restrict__ W1, const float* __restrict__ b1,
    const float* __restrict__ ac1, const float* __restrict__ W2,
    const float* __restrict__ b2, float* __restrict__ stat, int E) {
  __shared__ __align__(16) float As[129 * ASW];
  __shared__ int sdst[64], ssrc[64];
  stage_edges(ei, sorted, ea, h, E, blockIdx.x * 64, As, sdst, ssrc);
  int t = threadIdx.x, rg = t >> 3, cg = t & 7;
  float acc[2][8];
#pragma unroll
  for (int i = 0; i < 2; ++i)
#pragma unroll
    for (int j = 0; j < 8; ++j) acc[i][j] = b1[cg * 8 + j];
  gemm_r2c8(As, W1, 129, rg, cg, acc);
  __syncthreads();  // GEMM1 reads of As complete
  // BN1+relu -> Zs[k=col][e] overlaying As rows 0..63
#pragma unroll
  for (int j = 0; j < 8; ++j) {
    int cj = cg * 8 + j;
    float a1 = ac1[cj], c1 = ac1[64 + cj];
#pragma unroll
    for (int i = 0; i < 2; ++i)
      As[cj * ASW + rg * 2 + i] = fmaxf(acc[i][j] * a1 + c1, 0.f);
  }
  __syncthreads();
  float acc2[2][8];
#pragma unroll
  for (int i = 0; i < 2; ++i)
#pragma unroll
    for (int j = 0; j < 8; ++j) acc2[i][j] = b2[cg * 8 + j];
  gemm_r2c8(As, W2, 64, rg, cg, acc2);
  zero_invalid_rows(sdst, rg, acc2);
  stats_r2c8(acc2, stat + (size_t)(blockIdx.x & (NSH - 1)) * 128, t, cg);
}

__global__ __launch_bounds__(256) void edge_aggr_v3(
    const int* __restrict__ ei, const int* __restrict__ sorted,
    const float* __restrict__ ea, const float* __restrict__ h,
    const float* __restrict__ W1, const float* __restrict__ b1,
    const float* __restrict__ ac1, const float* __restrict__ W2,
    const float* __restrict__ b2, const float* __restrict__ ac2,
    float* __restrict__ aggr, int E) {
  __shared__ __align__(16) float As[129 * ASW];
  __shared__ int sdst[64], ssrc[64];
  stage_edges(ei, sorted, ea, h, E, blockIdx.x * 64, As, sdst, ssrc);
  int t = threadIdx.x, rg = t >> 3, cg = t & 7;
  float acc[2][8];
#pragma unroll
  for (int i = 0; i < 2; ++i)
#pragma unroll
    for (int j = 0; j < 8; ++j) acc[i][j] = b1[cg * 8 + j];
  gemm_r2c8(As, W1, 129, rg, cg, acc);
  __syncthreads();
#pragma unroll
  for (int j = 0; j < 8; ++j) {
    int cj = cg * 8 + j;
    float a1 = ac1[cj], c1 = ac1[64 + cj];
#pragma unroll
    for (int i = 0; i < 2; ++i)
      As[cj * ASW + rg * 2 + i] = fmaxf(acc[i][j] * a1 + c1, 0.f);
  }
  __syncthreads();
  float acc2[2][8];
#pragma unroll
  for (int i = 0; i < 2; ++i)
#pragma unroll
    for (int j = 0; j < 8; ++j) acc2[i][j] = b2[cg * 8 + j];
  gemm_r2c8(As, W2, 64, rg, cg, acc2);
  __syncthreads();  // GEMM2 reads of Zs complete
  // BN2+relu -> Ys[e][c] overlaying As rows 64..128
  float* Ys = As + 64 * ASW;
#pragma unroll
  for (int i = 0; i < 2; ++i) {
    int e = rg * 2 + i;
    bool v = sdst[e] >= 0;
#pragma unroll
    for (int j = 0; j < 8; ++j) {
      int cj = cg * 8 + j;
      Ys[e * ASW + cj] =
          v ? fmaxf(acc2[i][j] * ac2[cj] + ac2[64 + cj], 0.f) : 0.f;
    }
  }
  __syncthreads();
  // segmented sum over dst-sorted runs (cross-block partials via atomics)
  int col = t & 63, g = t >> 6;
  float s = 0.f;
  for (int e = g * 16; e < g * 16 + 16; ++e) {
    int d = sdst[e];
    s += Ys[e * ASW + col];
    int dn = (e == g * 16 + 15) ? -2 : sdst[e + 1];
    if (d != dn) {
      if (d >= 0) atomicAdd(&aggr[(size_t)d * 64 + col], s);
      s = 0.f;
    }
  }
}

// ---- node pipeline ---------------------------------------------------------

__global__ __launch_bounds__(256) void node_gemm1_v3(
    const float* __restrict__ h, const float* __restrict__ aggr,
    const float* __restrict__ W, const float* __restrict__ b,
    float* __restrict__ u1, float* __restrict__ stat, int N) {
  __shared__ __align__(16) float As[128 * ASW];
  int n0 = blockIdx.x * 64;
  int t = threadIdx.x;
  int c = t & 63, g = t >> 6;
  for (int n = g; n < 64; n += 4) {
    int idx = n0 + n;
    bool v = idx < N;
    As[c * ASW + n] = v ? h[(size_t)idx * 64 + c] : 0.f;
    As[(64 + c) * ASW + n] = v ? aggr[(size_t)idx * 64 + c] : 0.f;
  }
  __syncthreads();
  int rg = t >> 3, cg = t & 7;
  float acc[2][8];
#pragma unroll
  for (int i = 0; i < 2; ++i)
#pragma unroll
    for (int j = 0; j < 8; ++j) acc[i][j] = b[cg * 8 + j];
  gemm_r2c8(As, W, 128, rg, cg, acc);
#pragma unroll
  for (int i = 0; i < 2; ++i) {
    int idx = n0 + rg * 2 + i;
    if (idx < N) {
      *(float4*)&u1[(size_t)idx * 64 + cg * 8] =
          make_float4(acc[i][0], acc[i][1], acc[i][2], acc[i][3]);
      *(float4*)&u1[(size_t)idx * 64 + cg * 8 + 4] =
          make_float4(acc[i][4], acc[i][5], acc[i][6], acc[i][7]);
    } else {
#pragma unroll
      for (int j = 0; j < 8; ++j) acc[i][j] = 0.f;
    }
  }
  stats_r2c8(acc, stat + (size_t)(blockIdx.x & (NSH - 1)) * 128, t, cg);
}

__global__ __launch_bounds__(256) void node_gemm2_v3(
    const float* __restrict__ u1, const float* __restrict__ ac,
    const float* __restrict__ W, const float* __restrict__ b,
    float* __restrict__ u2, float* __restrict__ stat, int N) {
  __shared__ __align__(16) float As[64 * ASW];
  int n0 = blockIdx.x * 64;
  int t = threadIdx.x;
  int c = t & 63, g = t >> 6;
  float a1 = ac[c], c1 = ac[64 + c];
  for (int n = g; n < 64; n += 4) {
    int idx = n0 + n;
    bool v = idx < N;
    As[c * ASW + n] = v ? fmaxf(u1[(size_t)idx * 64 + c] * a1 + c1, 0.f) : 0.f;
  }
  __syncthreads();
  int rg = t >> 3, cg = t & 7;
  float acc[2][8];
#pragma unroll
  for (int i = 0; i < 2; ++i)
#pragma unroll
    for (int j = 0; j < 8; ++j) acc[i][j] = b[cg * 8 + j];
  gemm_r2c8(As, W, 64, rg, cg, acc);
#pragma unroll
  for (int i = 0; i < 2; ++i) {
    int idx = n0 + rg * 2 + i;
    if (idx < N) {
      *(float4*)&u2[(size_t)idx * 64 + cg * 8] =
          make_float4(acc[i][0], acc[i][1], acc[i][2], acc[i][3]);
      *(float4*)&u2[(size_t)idx * 64 + cg * 8 + 4] =
          make_float4(acc[i][4], acc[i][5], acc[i][6], acc[i][7]);
    } else {
#pragma unroll
      for (int j = 0; j < 8; ++j) acc[i][j] = 0.f;
    }
  }
  stats_r2c8(acc, stat + (size_t)(blockIdx.x & (NSH - 1)) * 128, t, cg);
}

__global__ void residual_kernel(float* __restrict__ h,
                                const float* __restrict__ u2,
                                const float* __restrict__ ac, int total) {
  int gid = blockIdx.x * blockDim.x + threadIdx.x;
  if (gid >= total) return;
  int o = gid & 63;
  float v = u2[gid] * ac[o] + ac[64 + o];
  h[gid] += fmaxf(v, 0.f);
}

__global__ void pred_kernel(const float* __restrict__ h,
                            const float* __restrict__ W,
                            const float* __restrict__ b,
                            float* __restrict__ out, int N) {
  int n = blockIdx.x * blockDim.x + threadIdx.x;
  if (n >= N) return;
  float acc = b[0];
  const float* hr = h + (size_t)n * 64;
#pragma unroll
  for (int o = 0; o < 64; ++o) acc += hr[o] * W[o];
  out[n] = acc;
}

// ---- launch ----------------------------------------------------------------

extern "C" void kernel_launch(void* const* d_in, const int* in_sizes, int n_in,
                              void* d_out, int out_size, void* d_ws,
                              size_t ws_size, hipStream_t stream) {
  const float* x = (const float*)d_in[0];
  const int* ei = (const int*)d_in[1];
  const float* ea = (const float*)d_in[2];
  const float* lin_W = (const float*)d_in[3];
  const float* lin_b = (const float*)d_in[4];
  const float* msg_W1 = (const float*)d_in[5];
  const float* msg_b1 = (const float*)d_in[6];
  const float* msg_g1 = (const float*)d_in[7];
  const float* msg_be1 = (const float*)d_in[8];
  const float* msg_W2 = (const float*)d_in[9];
  const float* msg_b2 = (const float*)d_in[10];
  const float* msg_g2 = (const float*)d_in[11];
  const float* msg_be2 = (const float*)d_in[12];
  const float* upd_W1 = (const float*)d_in[13];
  const float* upd_b1 = (const float*)d_in[14];
  const float* upd_g1 = (const float*)d_in[15];
  const float* upd_be1 = (const float*)d_in[16];
  const float* upd_W2 = (const float*)d_in[17];
  const float* upd_b2 = (const float*)d_in[18];
  const float* upd_g2 = (const float*)d_in[19];
  const float* upd_be2 = (const float*)d_in[20];
  const float* pred_W = (const float*)d_in[21];
  const float* pred_b = (const float*)d_in[22];
  float* out = (float*)d_out;

  const int N = in_sizes[0] / 6;
  const int E = in_sizes[1] / 2;
  const int L = 4;

  // workspace carve: ~59 MB
  char* p = (char*)d_ws;
  auto alloc = [&](size_t bytes) {
    void* r = (void*)p;
    p += (bytes + 255) & ~(size_t)255;
    return r;
  };
  float* h = (float*)alloc((size_t)N * 64 * 4);
  float* aggr = (float*)alloc((size_t)N * 64 * 4);
  float* u1 = (float*)alloc((size_t)N * 64 * 4);
  float* u2 = (float*)alloc((size_t)N * 64 * 4);
  float* stats = (float*)alloc((size_t)4 * NSH * 128 * 4);  // 4 regions
  float* ac1 = (float*)alloc(128 * 4);
  float* ac2 = (float*)alloc(128 * 4);
  float* acu1 = (float*)alloc(128 * 4);
  float* acu2 = (float*)alloc(128 * 4);
  int* deg = (int*)alloc((size_t)N * 4);
  int* offs = (int*)alloc((size_t)N * 4);
  int* cnt = (int*)alloc((size_t)N * 4);
  int* sorted = (int*)alloc((size_t)E * 4);

  const int B = 256;
  const size_t REG = (size_t)NSH * 128;  // floats per stat region
  int gridE256 = (E + 255) / 256;
  int gridE64 = (E + 63) / 64;
  int gridM64 = (N + 63) / 64;
  int gridN64 = (N * 64 + B - 1) / B;
  int gridN = (N + B - 1) / B;

  // setup
  hipMemsetAsync(deg, 0, (size_t)N * 4, stream);
  hipMemsetAsync(cnt, 0, (size_t)N * 4, stream);
  lin_in_kernel<<<gridN64, B, 0, stream>>>(x, lin_W, lin_b, h, N);
  deg_kernel<<<gridE256, B, 0, stream>>>(ei, deg, E);
  scan_kernel<<<1, 1024, 0, stream>>>(deg, offs, N);
  fill_kernel<<<gridE256, B, 0, stream>>>(ei, offs, cnt, sorted, E);

  for (int l = 0; l < L; ++l) {
    const float* W1 = msg_W1 + (size_t)l * 129 * 64;
    const float* W2 = msg_W2 + (size_t)l * 64 * 64;
    const float* U1 = upd_W1 + (size_t)l * 128 * 64;
    const float* U2 = upd_W2 + (size_t)l * 64 * 64;
    hipMemsetAsync(stats, 0, (size_t)4 * REG * 4, stream);
    hipMemsetAsync(aggr, 0, (size_t)N * 64 * 4, stream);
    edge_stats1_v3<<<gridE64, 256, 0, stream>>>(ei, sorted, ea, h, W1,
                                                msg_b1 + l * 64, stats, E);
    bn_finalize_kernel<<<1, 64, 0, stream>>>(stats, msg_g1 + l * 64,
                                             msg_be1 + l * 64, (float)E, ac1);
    edge_stats2_v3<<<gridE64, 256, 0, stream>>>(
        ei, sorted, ea, h, W1, msg_b1 + l * 64, ac1, W2, msg_b2 + l * 64,
        stats + REG, E);
    bn_finalize_kernel<<<1, 64, 0, stream>>>(stats + REG, msg_g2 + l * 64,
                                             msg_be2 + l * 64, (float)E, ac2);
    edge_aggr_v3<<<gridE64, 256, 0, stream>>>(ei, sorted, ea, h, W1,
                                              msg_b1 + l * 64, ac1, W2,
                                              msg_b2 + l * 64, ac2, aggr, E);
    node_gemm1_v3<<<gridM64, 256, 0, stream>>>(h, aggr, U1, upd_b1 + l * 64,
                                               u1, stats + 2 * REG, N);
    bn_finalize_kernel<<<1, 64, 0, stream>>>(stats + 2 * REG, upd_g1 + l * 64,
                                             upd_be1 + l * 64, (float)N, acu1);
    node_gemm2_v3<<<gridM64, 256, 0, stream>>>(u1, acu1, U2, upd_b2 + l * 64,
                                               u2, stats + 3 * REG, N);
    bn_finalize_kernel<<<1, 64, 0, stream>>>(stats + 3 * REG, upd_g2 + l * 64,
                                             upd_be2 + l * 64, (float)N, acu2);
    residual_kernel<<<gridN64, B, 0, stream>>>(h, u2, acu2, N * 64);
  }
  pred_kernel<<<gridN, B, 0, stream>>>(h, pred_W, pred_b, out, N);
}

// Round 6
// 2780.604 us; speedup vs baseline: 35.0584x; 5.2727x over previous
//
#include <hip/hip_runtime.h>
#include <hip/hip_bf16.h>

// MPNN, fp32 tensors / int32 edge_index. Round-6: edge MLPs on bf16 MFMA
// (16x16x32), A-frags gathered straight from global h_bf (no LDS staging),
// B-frags from pre-packed n-major bf16 weights. BN two-pass via stored y
// (bf16, in-place y1->y2) when ws_size permits, else MFMA recompute.
// Node MLPs stay fp32 (v3 tiled). Stats sharded 128-way (round-5 fix).

#define BN_EPS 1e-5f
#define NSH 128
#define LYS 80   // LDS y-tile row stride in shorts (16B-aligned rows)
#define ASW 66   // node-kernel LDS stride (round-5)

typedef __attribute__((ext_vector_type(8))) short short8;
typedef __attribute__((ext_vector_type(4))) float floatx4;

__device__ __forceinline__ short f2bs(float f) {
  union { float f; unsigned u; } x; x.f = f;
  unsigned r = x.u + 0x7fffu + ((x.u >> 16) & 1u);
  return (short)(r >> 16);
}
__device__ __forceinline__ float bs2f(short s) {
  union { unsigned u; float f; } x;
  x.u = ((unsigned)(unsigned short)s) << 16;
  return x.f;
}

// ---- setup kernels ---------------------------------------------------------

__global__ void lin_in_kernel(const float* __restrict__ x,
                              const float* __restrict__ W,
                              const float* __restrict__ b, float* __restrict__ h,
                              short* __restrict__ hb, int N) {
  int gid = blockIdx.x * blockDim.x + threadIdx.x;
  if (gid >= N * 64) return;
  int n = gid >> 6, o = gid & 63;
  float acc = b[o];
#pragma unroll
  for (int k = 0; k < 6; ++k) acc += x[n * 6 + k] * W[k * 64 + o];
  h[gid] = acc;
  hb[gid] = f2bs(acc);
}

__global__ void deg_kernel(const int* __restrict__ ei, int* __restrict__ deg,
                           int E) {
  int gid = blockIdx.x * blockDim.x + threadIdx.x;
  if (gid < E) atomicAdd(&deg[ei[E + gid]], 1);  // row 1 = dst
}

__global__ void scan_kernel(const int* __restrict__ deg, int* __restrict__ offs,
                            int N) {
  __shared__ int s[1024];
  int t = threadIdx.x;
  int chunk = (N + 1023) >> 10;
  int lo = t * chunk, hi = lo + chunk;
  if (hi > N) hi = N;
  if (lo > N) lo = N;
  int tot = 0;
  for (int i = lo; i < hi; ++i) tot += deg[i];
  s[t] = tot;
  __syncthreads();
  for (int off = 1; off < 1024; off <<= 1) {
    int v = (t >= off) ? s[t - off] : 0;
    __syncthreads();
    s[t] += v;
    __syncthreads();
  }
  int run = s[t] - tot;
  for (int i = lo; i < hi; ++i) {
    offs[i] = run;
    run += deg[i];
  }
}

__global__ void fill_kernel(const int* __restrict__ ei,
                            const int* __restrict__ offs, int* __restrict__ cnt,
                            int* __restrict__ sorted, int E) {
  int gid = blockIdx.x * blockDim.x + threadIdx.x;
  if (gid >= E) return;
  int d = ei[E + gid];
  int pos = offs[d] + atomicAdd(&cnt[d], 1);
  sorted[pos] = gid;
}

// pre-gather sorted dst/src/ea (padded to Epad; pad: dst=-1, src=0, ea=0)
__global__ void gather_edges_kernel(const int* __restrict__ ei,
                                    const int* __restrict__ sorted,
                                    const float* __restrict__ ea,
                                    int* __restrict__ dd, int* __restrict__ ds,
                                    short* __restrict__ es, int E, int Epad) {
  int i = blockIdx.x * 256 + threadIdx.x;
  if (i >= Epad) return;
  if (i < E) {
    int e = sorted[i];
    dd[i] = ei[E + e];
    ds[i] = ei[e];
    es[i] = f2bs(ea[e]);
  } else {
    dd[i] = -1;
    ds[i] = 0;
    es[i] = 0;
  }
}

// msg_W1 (L,129,64) -> Wt1 (L,64,160) bf16 n-major, k zero-padded
__global__ void pack_w1_kernel(const float* __restrict__ W,
                               short* __restrict__ Wt, int L_) {
  int i = blockIdx.x * 256 + threadIdx.x;
  if (i >= L_ * 64 * 160) return;
  int k = i % 160, n = (i / 160) % 64, l = i / (160 * 64);
  Wt[i] = (k < 129) ? f2bs(W[((size_t)l * 129 + k) * 64 + n]) : (short)0;
}

// msg_W2 (L,64,64) -> Wt2 (L,64,64) bf16 n-major
__global__ void pack_w2_kernel(const float* __restrict__ W,
                               short* __restrict__ Wt, int L_) {
  int i = blockIdx.x * 256 + threadIdx.x;
  if (i >= L_ * 64 * 64) return;
  int k = i % 64, n = (i / 64) % 64, l = i / 4096;
  Wt[i] = f2bs(W[((size_t)l * 64 + k) * 64 + n]);
}

// reduce NSH shards -> BN scale/shift
__global__ void bn_finalize_kernel(const float* __restrict__ shards,
                                   const float* __restrict__ gamma,
                                   const float* __restrict__ beta, float cnt,
                                   float* __restrict__ ac) {
  int o = threadIdx.x;  // 64 threads
  float s = 0.f, q = 0.f;
  for (int i = 0; i < NSH; ++i) {
    s += shards[i * 128 + o];
    q += shards[i * 128 + 64 + o];
  }
  float mu = s / cnt;
  float var = fmaxf(q / cnt - mu * mu, 0.f);
  float r = rsqrtf(var + BN_EPS);
  float g = gamma[o];
  ac[o] = g * r;
  ac[64 + o] = beta[o] - mu * g * r;
}

// ---- MFMA edge helpers -----------------------------------------------------
// Block 256 thr = 4 waves. Wave w owns C cols [16w,16w+16). Per wave 4 m-tiles
// (16 edges each). C layout: col=lane&15, row=quad*4+reg. A: A[m=lane&15][k=quad*8+j].

__device__ __forceinline__ void edge_gemm1_mfma(
    const short* __restrict__ hbf, const short* __restrict__ Wt1,
    const float* __restrict__ b1, const int* sdst, const int* ssrc,
    const short* sea, int w, int n16, int quad, floatx4 acc[4]) {
  short8 B[5];
  const short* wp = Wt1 + (w * 16 + n16) * 160 + quad * 8;
#pragma unroll
  for (int ks = 0; ks < 5; ++ks) B[ks] = *(const short8*)(wp + ks * 32);
  float bias = b1[w * 16 + n16];
#pragma unroll
  for (int tm = 0; tm < 4; ++tm) {
    floatx4 z = {bias, bias, bias, bias};
    acc[tm] = z;
  }
#pragma unroll
  for (int tm = 0; tm < 4; ++tm) {
    int e = tm * 16 + n16;
    int d = sdst[e];
    d = d < 0 ? 0 : d;
    int sidx = ssrc[e];
    const short* hd = hbf + (size_t)d * 64 + quad * 8;
    const short* hs = hbf + (size_t)sidx * 64 + quad * 8;
    short8 a0 = *(const short8*)hd;
    short8 a1 = *(const short8*)(hd + 32);
    short8 a2 = *(const short8*)hs;
    short8 a3 = *(const short8*)(hs + 32);
    short8 a4 = {0, 0, 0, 0, 0, 0, 0, 0};
    if (quad == 0) a4[0] = sea[e];
    acc[tm] = __builtin_amdgcn_mfma_f32_16x16x32_bf16(a0, B[0], acc[tm], 0, 0, 0);
    acc[tm] = __builtin_amdgcn_mfma_f32_16x16x32_bf16(a1, B[1], acc[tm], 0, 0, 0);
    acc[tm] = __builtin_amdgcn_mfma_f32_16x16x32_bf16(a2, B[2], acc[tm], 0, 0, 0);
    acc[tm] = __builtin_amdgcn_mfma_f32_16x16x32_bf16(a3, B[3], acc[tm], 0, 0, 0);
    acc[tm] = __builtin_amdgcn_mfma_f32_16x16x32_bf16(a4, B[4], acc[tm], 0, 0, 0);
  }
}

// column sum/sumsq from C-frags (invalid rows excluded) -> sharded atomics
__device__ __forceinline__ void edge_stats_mfma(const floatx4 acc[4], int idx0,
                                                int E, int w, int n16, int quad,
                                                int ln, float* shard) {
  float s = 0.f, q = 0.f;
#pragma unroll
  for (int tm = 0; tm < 4; ++tm)
#pragma unroll
    for (int r = 0; r < 4; ++r) {
      int el = tm * 16 + quad * 4 + r;
      float v = (idx0 + el < E) ? acc[tm][r] : 0.f;
      s += v;
      q += v * v;
    }
  s += __shfl_down(s, 32, 64);
  q += __shfl_down(q, 32, 64);
  s += __shfl_down(s, 16, 64);
  q += __shfl_down(q, 16, 64);
  if (ln < 16) {
    atomicAdd(&shard[w * 16 + ln], s);
    atomicAdd(&shard[64 + w * 16 + ln], q);
  }
}

__device__ __forceinline__ void accs_to_ly(const floatx4 acc[4], short* Ly,
                                           int w, int n16, int quad) {
#pragma unroll
  for (int tm = 0; tm < 4; ++tm)
#pragma unroll
    for (int r = 0; r < 4; ++r) {
      int row = tm * 16 + quad * 4 + r;
      Ly[row * LYS + w * 16 + n16] = f2bs(acc[tm][r]);
    }
}

__device__ __forceinline__ void ly_to_global(const short* Ly, short* y,
                                             int idx0, int t) {
#pragma unroll
  for (int it = 0; it < 2; ++it) {
    int r = t >> 2, seg = (t & 3) * 16 + it * 8;
    *(uint4*)&y[(size_t)(idx0 + r) * 64 + seg] = *(const uint4*)&Ly[r * LYS + seg];
  }
}

// ---- edge pass kernels -----------------------------------------------------

template <bool STOREY>
__global__ __launch_bounds__(256) void edge_pass_a(
    const short* __restrict__ hbf, const short* __restrict__ Wt1,
    const float* __restrict__ b1, const int* __restrict__ dd,
    const int* __restrict__ dsr, const short* __restrict__ es,
    float* __restrict__ stat, short* __restrict__ y, int E) {
  __shared__ int sdst[64], ssrc[64];
  __shared__ short sea[64];
  __shared__ __align__(16) short Ly[64 * LYS];
  int t = threadIdx.x, idx0 = blockIdx.x * 64;
  if (t < 64) {
    sdst[t] = dd[idx0 + t];
    ssrc[t] = dsr[idx0 + t];
    sea[t] = es[idx0 + t];
  }
  __syncthreads();
  int w = t >> 6, ln = t & 63, n16 = ln & 15, quad = ln >> 4;
  floatx4 acc[4];
  edge_gemm1_mfma(hbf, Wt1, b1, sdst, ssrc, sea, w, n16, quad, acc);
  edge_stats_mfma(acc, idx0, E, w, n16, quad, ln,
                  stat + (size_t)(blockIdx.x & (NSH - 1)) * 128);
  if (STOREY) {
    accs_to_ly(acc, Ly, w, n16, quad);
    __syncthreads();
    ly_to_global(Ly, y, idx0, t);
  }
}

__global__ __launch_bounds__(256) void edge_pass_b_store(
    short* y, const float* __restrict__ ac1, const short* __restrict__ Wt2,
    const float* __restrict__ b2, float* __restrict__ stat, int E) {
  __shared__ __align__(16) short Ly[64 * LYS];
  int t = threadIdx.x, idx0 = blockIdx.x * 64;
  int w = t >> 6, ln = t & 63, n16 = ln & 15, quad = ln >> 4;
  short8 B[2];
  const short* wp = Wt2 + (w * 16 + n16) * 64 + quad * 8;
  B[0] = *(const short8*)wp;
  B[1] = *(const short8*)(wp + 32);
  float a1v[2][8], c1v[2][8];
#pragma unroll
  for (int ks = 0; ks < 2; ++ks) {
    int k0 = ks * 32 + quad * 8;
#pragma unroll
    for (int j = 0; j < 8; ++j) {
      a1v[ks][j] = ac1[k0 + j];
      c1v[ks][j] = ac1[64 + k0 + j];
    }
  }
  float bias = b2[w * 16 + n16];
  floatx4 acc[4];
#pragma unroll
  for (int tm = 0; tm < 4; ++tm) {
    floatx4 z = {bias, bias, bias, bias};
    acc[tm] = z;
  }
#pragma unroll
  for (int tm = 0; tm < 4; ++tm) {
    const short* yr = y + (size_t)(idx0 + tm * 16 + n16) * 64 + quad * 8;
#pragma unroll
    for (int ks = 0; ks < 2; ++ks) {
      short8 raw = *(const short8*)(yr + ks * 32);
      short8 z;
#pragma unroll
      for (int j = 0; j < 8; ++j)
        z[j] = f2bs(fmaxf(bs2f(raw[j]) * a1v[ks][j] + c1v[ks][j], 0.f));
      acc[tm] = __builtin_amdgcn_mfma_f32_16x16x32_bf16(z, B[ks], acc[tm], 0, 0, 0);
    }
  }
  edge_stats_mfma(acc, idx0, E, w, n16, quad, ln,
                  stat + (size_t)(blockIdx.x & (NSH - 1)) * 128);
  accs_to_ly(acc, Ly, w, n16, quad);
  __syncthreads();      // all reads of this block's y rows complete
  ly_to_global(Ly, y, idx0, t);  // in-place y1 -> y2
}

__global__ __launch_bounds__(256) void edge_pass_c_store(
    const short* __restrict__ y, const float* __restrict__ ac2,
    const int* __restrict__ dd, float* __restrict__ aggr, int Epad) {
  __shared__ int cd[256];
  int t = threadIdx.x, idx0 = blockIdx.x * 256;
  cd[t] = (idx0 + t < Epad) ? dd[idx0 + t] : -1;
  __syncthreads();
  int col = t & 63, g = t >> 6;
  float a2 = ac2[col], c2 = ac2[64 + col];
  float s = 0.f;
  int e0 = g * 64;
  for (int e = e0; e < e0 + 64; ++e) {
    int d = cd[e];
    if (d >= 0)
      s += fmaxf(bs2f(y[(size_t)(idx0 + e) * 64 + col]) * a2 + c2, 0.f);
    int dn = (e == e0 + 63) ? -2 : cd[e + 1];
    if (d != dn) {
      if (d >= 0) atomicAdd(&aggr[(size_t)d * 64 + col], s);
      s = 0.f;
    }
  }
}

// fallback (no y buffer): recompute GEMM1, LDS round-trip, GEMM2
__global__ __launch_bounds__(256) void edge_pass_b_rec(
    const short* __restrict__ hbf, const short* __restrict__ Wt1,
    const float* __restrict__ b1, const int* __restrict__ dd,
    const int* __restrict__ dsr, const short* __restrict__ es,
    const float* __restrict__ ac1, const short* __restrict__ Wt2,
    const float* __restrict__ b2, float* __restrict__ stat, int E) {
  __shared__ int sdst[64], ssrc[64];
  __shared__ short sea[64];
  __shared__ __align__(16) short Ly[64 * LYS];
  int t = threadIdx.x, idx0 = blockIdx.x * 64;
  if (t < 64) {
    sdst[t] = dd[idx0 + t];
    ssrc[t] = dsr[idx0 + t];
    sea[t] = es[idx0 + t];
  }
  __syncthreads();
  int w = t >> 6, ln = t & 63, n16 = ln & 15, quad = ln >> 4;
  floatx4 acc[4];
  edge_gemm1_mfma(hbf, Wt1, b1, sdst, ssrc, sea, w, n16, quad, acc);
  float a1 = ac1[w * 16 + n16], c1 = ac1[64 + w * 16 + n16];
#pragma unroll
  for (int tm = 0; tm < 4; ++tm)
#pragma unroll
    for (int r = 0; r < 4; ++r) acc[tm][r] = fmaxf(acc[tm][r] * a1 + c1, 0.f);
  accs_to_ly(acc, Ly, w, n16, quad);
  __syncthreads();
  short8 B[2];
  const short* wp = Wt2 + (w * 16 + n16) * 64 + quad * 8;
  B[0] = *(const short8*)wp;
  B[1] = *(const short8*)(wp + 32);
  float bias = b2[w * 16 + n16];
  floatx4 acc2[4];
#pragma unroll
  for (int tm = 0; tm < 4; ++tm) {
    floatx4 z = {bias, bias, bias, bias};
    acc2[tm] = z;
  }
#pragma unroll
  for (int tm = 0; tm < 4; ++tm)
#pragma unroll
    for (int ks = 0; ks < 2; ++ks) {
      short8 a = *(const short8*)&Ly[(tm * 16 + n16) * LYS + ks * 32 + quad * 8];
      acc2[tm] = __builtin_amdgcn_mfma_f32_16x16x32_bf16(a, B[ks], acc2[tm], 0, 0, 0);
    }
  edge_stats_mfma(acc2, idx0, E, w, n16, quad, ln,
                  stat + (size_t)(blockIdx.x & (NSH - 1)) * 128);
}

__global__ __launch_bounds__(256) void edge_pass_c_rec(
    const short* __restrict__ hbf, const short* __restrict__ Wt1,
    const float* __restrict__ b1, const int* __restrict__ dd,
    const int* __restrict__ dsr, const short* __restrict__ es,
    const float* __restrict__ ac1, const short* __restrict__ Wt2,
    const float* __restrict__ b2, const float* __restrict__ ac2,
    float* __restrict__ aggr, int E) {
  __shared__ int sdst[64], ssrc[64];
  __shared__ short sea[64];
  __shared__ __align__(16) short Ly[64 * LYS];
  int t = threadIdx.x, idx0 = blockIdx.x * 64;
  if (t < 64) {
    sdst[t] = dd[idx0 + t];
    ssrc[t] = dsr[idx0 + t];
    sea[t] = es[idx0 + t];
  }
  __syncthreads();
  int w = t >> 6, ln = t & 63, n16 = ln & 15, quad = ln >> 4;
  floatx4 acc[4];
  edge_gemm1_mfma(hbf, Wt1, b1, sdst, ssrc, sea, w, n16, quad, acc);
  float a1 = ac1[w * 16 + n16], c1 = ac1[64 + w * 16 + n16];
#pragma unroll
  for (int tm = 0; tm < 4; ++tm)
#pragma unroll
    for (int r = 0; r < 4; ++r) acc[tm][r] = fmaxf(acc[tm][r] * a1 + c1, 0.f);
  accs_to_ly(acc, Ly, w, n16, quad);
  __syncthreads();
  short8 B[2];
  const short* wp = Wt2 + (w * 16 + n16) * 64 + quad * 8;
  B[0] = *(const short8*)wp;
  B[1] = *(const short8*)(wp + 32);
  float bias = b2[w * 16 + n16];
  floatx4 acc2[4];
#pragma unroll
  for (int tm = 0; tm < 4; ++tm) {
    floatx4 z = {bias, bias, bias, bias};
    acc2[tm] = z;
  }
#pragma unroll
  for (int tm = 0; tm < 4; ++tm)
#pragma unroll
    for (int ks = 0; ks < 2; ++ks) {
      short8 a = *(const short8*)&Ly[(tm * 16 + n16) * LYS + ks * 32 + quad * 8];
      acc2[tm] = __builtin_amdgcn_mfma_f32_16x16x32_bf16(a, B[ks], acc2[tm], 0, 0, 0);
    }
  __syncthreads();  // done reading z from Ly
  float a2 = ac2[w * 16 + n16], c2 = ac2[64 + w * 16 + n16];
#pragma unroll
  for (int tm = 0; tm < 4; ++tm)
#pragma unroll
    for (int r = 0; r < 4; ++r) {
      float v = fmaxf(acc2[tm][r] * a2 + c2, 0.f);
      acc2[tm][r] = (idx0 + tm * 16 + quad * 4 + r < E) ? v : 0.f;
    }
  accs_to_ly(acc2, Ly, w, n16, quad);
  __syncthreads();
  int col = t & 63, g = t >> 6;
  float s = 0.f;
  int e0 = g * 16;
  for (int e = e0; e < e0 + 16; ++e) {
    int d = sdst[e];
    s += bs2f(Ly[e * LYS + col]);
    int dn = (e == e0 + 15) ? -2 : sdst[e + 1];
    if (d != dn) {
      if (d >= 0) atomicAdd(&aggr[(size_t)d * 64 + col], s);
      s = 0.f;
    }
  }
}

// ---- node pipeline (round-5 fp32 tiled, unchanged) -------------------------

__device__ __forceinline__ void gemm_r2c8(const float* __restrict__ As,
                                          const float* __restrict__ W, int K,
                                          int rg, int cg, float acc[2][8]) {
  const float* ap = As + rg * 2;
  const float* wp = W + cg * 8;
#pragma unroll 4
  for (int k = 0; k < K; ++k) {
    float2 a = *(const float2*)&ap[k * ASW];
    float4 w0 = *(const float4*)&wp[k * 64];
    float4 w1 = *(const float4*)&wp[k * 64 + 4];
    float wv[8] = {w0.x, w0.y, w0.z, w0.w, w1.x, w1.y, w1.z, w1.w};
#pragma unroll
    for (int j = 0; j < 8; ++j) {
      acc[0][j] += a.x * wv[j];
      acc[1][j] += a.y * wv[j];
    }
  }
}

__device__ __forceinline__ void stats_r2c8(const float acc[2][8],
                                           float* __restrict__ shard, int t,
                                           int cg) {
  float s[8], q[8];
#pragma unroll
  for (int j = 0; j < 8; ++j) {
    s[j] = acc[0][j] + acc[1][j];
    q[j] = acc[0][j] * acc[0][j] + acc[1][j] * acc[1][j];
  }
#pragma unroll
  for (int off = 32; off >= 8; off >>= 1) {
#pragma unroll
    for (int j = 0; j < 8; ++j) {
      s[j] += __shfl_down(s[j], off, 64);
      q[j] += __shfl_down(q[j], off, 64);
    }
  }
  if (((t & 63) >> 3) == 0) {
#pragma unroll
    for (int j = 0; j < 8; ++j) {
      atomicAdd(&shard[cg * 8 + j], s[j]);
      atomicAdd(&shard[64 + cg * 8 + j], q[j]);
    }
  }
}

__global__ __launch_bounds__(256) void node_gemm1_v3(
    const float* __restrict__ h, const float* __restrict__ aggr,
    const float* __restrict__ W, const float* __restrict__ b,
    float* __restrict__ u1, float* __restrict__ stat, int N) {
  __shared__ __align__(16) float As[128 * ASW];
  int n0 = blockIdx.x * 64;
  int t = threadIdx.x;
  int c = t & 63, g = t >> 6;
  for (int n = g; n < 64; n += 4) {
    int idx = n0 + n;
    bool v = idx < N;
    As[c * ASW + n] = v ? h[(size_t)idx * 64 + c] : 0.f;
    As[(64 + c) * ASW + n] = v ? aggr[(size_t)idx * 64 + c] : 0.f;
  }
  __syncthreads();
  int rg = t >> 3, cg = t & 7;
  float acc[2][8];
#pragma unroll
  for (int i = 0; i < 2; ++i)
#pragma unroll
    for (int j = 0; j < 8; ++j) acc[i][j] = b[cg * 8 + j];
  gemm_r2c8(As, W, 128, rg, cg, acc);
#pragma unroll
  for (int i = 0; i < 2; ++i) {
    int idx = n0 + rg * 2 + i;
    if (idx < N) {
      *(float4*)&u1[(size_t)idx * 64 + cg * 8] =
          make_float4(acc[i][0], acc[i][1], acc[i][2], acc[i][3]);
      *(float4*)&u1[(size_t)idx * 64 + cg * 8 + 4] =
          make_float4(acc[i][4], acc[i][5], acc[i][6], acc[i][7]);
    } else {
#pragma unroll
      for (int j = 0; j < 8; ++j) acc[i][j] = 0.f;
    }
  }
  stats_r2c8(acc, stat + (size_t)(blockIdx.x & (NSH - 1)) * 128, t, cg);
}

__global__ __launch_bounds__(256) void node_gemm2_v3(
    const float* __restrict__ u1, const float* __restrict__ ac,
    const float* __restrict__ W, const float* __restrict__ b,
    float* __restrict__ u2, float* __restrict__ stat, int N) {
  __shared__ __align__(16) float As[64 * ASW];
  int n0 = blockIdx.x * 64;
  int t = threadIdx.x;
  int c = t & 63, g = t >> 6;
  float a1 = ac[c], c1 = ac[64 + c];
  for (int n = g; n < 64; n += 4) {
    int idx = n0 + n;
    bool v = idx < N;
    As[c * ASW + n] = v ? fmaxf(u1[(size_t)idx * 64 + c] * a1 + c1, 0.f) : 0.f;
  }
  __syncthreads();
  int rg = t >> 3, cg = t & 7;
  float acc[2][8];
#pragma unroll
  for (int i = 0; i < 2; ++i)
#pragma unroll
    for (int j = 0; j < 8; ++j) acc[i][j] = b[cg * 8 + j];
  gemm_r2c8(As, W, 64, rg, cg, acc);
#pragma unroll
  for (int i = 0; i < 2; ++i) {
    int idx = n0 + rg * 2 + i;
    if (idx < N) {
      *(float4*)&u2[(size_t)idx * 64 + cg * 8] =
          make_float4(acc[i][0], acc[i][1], acc[i][2], acc[i][3]);
      *(float4*)&u2[(size_t)idx * 64 + cg * 8 + 4] =
          make_float4(acc[i][4], acc[i][5], acc[i][6], acc[i][7]);
    } else {
#pragma unroll
      for (int j = 0; j < 8; ++j) acc[i][j] = 0.f;
    }
  }
  stats_r2c8(acc, stat + (size_t)(blockIdx.x & (NSH - 1)) * 128, t, cg);
}

__global__ void residual_kernel(float* __restrict__ h, short* __restrict__ hb,
                                const float* __restrict__ u2,
                                const float* __restrict__ ac, int total) {
  int gid = blockIdx.x * blockDim.x + threadIdx.x;
  if (gid >= total) return;
  int o = gid & 63;
  float v = u2[gid] * ac[o] + ac[64 + o];
  float nv = h[gid] + fmaxf(v, 0.f);
  h[gid] = nv;
  hb[gid] = f2bs(nv);
}

__global__ void pred_kernel(const float* __restrict__ h,
                            const float* __restrict__ W,
                            const float* __restrict__ b,
                            float* __restrict__ out, int N) {
  int n = blockIdx.x * blockDim.x + threadIdx.x;
  if (n >= N) return;
  float acc = b[0];
  const float* hr = h + (size_t)n * 64;
#pragma unroll
  for (int o = 0; o < 64; ++o) acc += hr[o] * W[o];
  out[n] = acc;
}

// ---- launch ----------------------------------------------------------------

extern "C" void kernel_launch(void* const* d_in, const int* in_sizes, int n_in,
                              void* d_out, int out_size, void* d_ws,
                              size_t ws_size, hipStream_t stream) {
  const float* x = (const float*)d_in[0];
  const int* ei = (const int*)d_in[1];
  const float* ea = (const float*)d_in[2];
  const float* lin_W = (const float*)d_in[3];
  const float* lin_b = (const float*)d_in[4];
  const float* msg_W1 = (const float*)d_in[5];
  const float* msg_b1 = (const float*)d_in[6];
  const float* msg_g1 = (const float*)d_in[7];
  const float* msg_be1 = (const float*)d_in[8];
  const float* msg_W2 = (const float*)d_in[9];
  const float* msg_b2 = (const float*)d_in[10];
  const float* msg_g2 = (const float*)d_in[11];
  const float* msg_be2 = (const float*)d_in[12];
  const float* upd_W1 = (const float*)d_in[13];
  const float* upd_b1 = (const float*)d_in[14];
  const float* upd_g1 = (const float*)d_in[15];
  const float* upd_be1 = (const float*)d_in[16];
  const float* upd_W2 = (const float*)d_in[17];
  const float* upd_b2 = (const float*)d_in[18];
  const float* upd_g2 = (const float*)d_in[19];
  const float* upd_be2 = (const float*)d_in[20];
  const float* pred_W = (const float*)d_in[21];
  const float* pred_b = (const float*)d_in[22];
  float* out = (float*)d_out;

  const int N = in_sizes[0] / 6;
  const int E = in_sizes[1] / 2;
  const int L = 4;
  const int Epad = ((E + 63) / 64) * 64;

  char* p = (char*)d_ws;
  auto alloc = [&](size_t bytes) {
    void* r = (void*)p;
    p += (bytes + 255) & ~(size_t)255;
    return r;
  };
  float* h = (float*)alloc((size_t)N * 64 * 4);
  short* hb = (short*)alloc((size_t)N * 64 * 2);
  float* aggr = (float*)alloc((size_t)N * 64 * 4);
  float* u1 = (float*)alloc((size_t)N * 64 * 4);
  float* u2 = (float*)alloc((size_t)N * 64 * 4);
  float* stats = (float*)alloc((size_t)4 * NSH * 128 * 4);
  float* ac1 = (float*)alloc(128 * 4);
  float* ac2 = (float*)alloc(128 * 4);
  float* acu1 = (float*)alloc(128 * 4);
  float* acu2 = (float*)alloc(128 * 4);
  int* deg = (int*)alloc((size_t)N * 4);
  int* offs = (int*)alloc((size_t)N * 4);
  int* cnt = (int*)alloc((size_t)N * 4);
  int* sorted = (int*)alloc((size_t)E * 4);
  int* dd = (int*)alloc((size_t)Epad * 4);
  int* dsr = (int*)alloc((size_t)Epad * 4);
  short* es = (short*)alloc((size_t)Epad * 2);
  short* Wt1 = (short*)alloc((size_t)L * 64 * 160 * 2);
  short* Wt2 = (short*)alloc((size_t)L * 64 * 64 * 2);

  size_t base_bytes = (size_t)(p - (char*)d_ws);
  bool storey = (base_bytes + (size_t)Epad * 64 * 2 + 4096) <= ws_size;
  short* y = storey ? (short*)alloc((size_t)Epad * 64 * 2) : (short*)nullptr;

  const int B = 256;
  const size_t REG = (size_t)NSH * 128;
  int gridE256 = (E + 255) / 256;
  int gridEb = Epad / 64;
  int gridEc = (Epad + 255) / 256;
  int gridM64 = (N + 63) / 64;
  int gridN64 = (N * 64 + B - 1) / B;
  int gridN = (N + B - 1) / B;

  // setup
  hipMemsetAsync(deg, 0, (size_t)N * 4, stream);
  hipMemsetAsync(cnt, 0, (size_t)N * 4, stream);
  lin_in_kernel<<<gridN64, B, 0, stream>>>(x, lin_W, lin_b, h, hb, N);
  deg_kernel<<<gridE256, B, 0, stream>>>(ei, deg, E);
  scan_kernel<<<1, 1024, 0, stream>>>(deg, offs, N);
  fill_kernel<<<gridE256, B, 0, stream>>>(ei, offs, cnt, sorted, E);
  gather_edges_kernel<<<gridEc, B, 0, stream>>>(ei, sorted, ea, dd, dsr, es, E,
                                                Epad);
  pack_w1_kernel<<<(L * 64 * 160 + 255) / 256, B, 0, stream>>>(msg_W1, Wt1, L);
  pack_w2_kernel<<<(L * 64 * 64 + 255) / 256, B, 0, stream>>>(msg_W2, Wt2, L);

  for (int l = 0; l < L; ++l) {
    const short* Wt1l = Wt1 + (size_t)l * 64 * 160;
    const short* Wt2l = Wt2 + (size_t)l * 64 * 64;
    const float* U1 = upd_W1 + (size_t)l * 128 * 64;
    const float* U2 = upd_W2 + (size_t)l * 64 * 64;
    hipMemsetAsync(stats, 0, (size_t)4 * REG * 4, stream);
    hipMemsetAsync(aggr, 0, (size_t)N * 64 * 4, stream);
    if (storey) {
      edge_pass_a<true><<<gridEb, 256, 0, stream>>>(
          hb, Wt1l, msg_b1 + l * 64, dd, dsr, es, stats, y, E);
      bn_finalize_kernel<<<1, 64, 0, stream>>>(stats, msg_g1 + l * 64,
                                               msg_be1 + l * 64, (float)E, ac1);
      edge_pass_b_store<<<gridEb, 256, 0, stream>>>(y, ac1, Wt2l,
                                                    msg_b2 + l * 64,
                                                    stats + REG, E);
      bn_finalize_kernel<<<1, 64, 0, stream>>>(stats + REG, msg_g2 + l * 64,
                                               msg_be2 + l * 64, (float)E, ac2);
      edge_pass_c_store<<<gridEc, 256, 0, stream>>>(y, ac2, dd, aggr, Epad);
    } else {
      edge_pass_a<false><<<gridEb, 256, 0, stream>>>(
          hb, Wt1l, msg_b1 + l * 64, dd, dsr, es, stats, (short*)nullptr, E);
      bn_finalize_kernel<<<1, 64, 0, stream>>>(stats, msg_g1 + l * 64,
                                               msg_be1 + l * 64, (float)E, ac1);
      edge_pass_b_rec<<<gridEb, 256, 0, stream>>>(
          hb, Wt1l, msg_b1 + l * 64, dd, dsr, es, ac1, Wt2l, msg_b2 + l * 64,
          stats + REG, E);
      bn_finalize_kernel<<<1, 64, 0, stream>>>(stats + REG, msg_g2 + l * 64,
                                               msg_be2 + l * 64, (float)E, ac2);
      edge_pass_c_rec<<<gridEb, 256, 0, stream>>>(
          hb, Wt1l, msg_b1 + l * 64, dd, dsr, es, ac1, Wt2l, msg_b2 + l * 64,
          ac2, aggr, E);
    }
    node_gemm1_v3<<<gridM64, 256, 0, stream>>>(h, aggr, U1, upd_b1 + l * 64,
                                               u1, stats + 2 * REG, N);
    bn_finalize_kernel<<<1, 64, 0, stream>>>(stats + 2 * REG, upd_g1 + l * 64,
                                             upd_be1 + l * 64, (float)N, acu1);
    node_gemm2_v3<<<gridM64, 256, 0, stream>>>(u1, acu1, U2, upd_b2 + l * 64,
                                               u2, stats + 3 * REG, N);
    bn_finalize_kernel<<<1, 64, 0, stream>>>(stats + 3 * REG, upd_g2 + l * 64,
                                             upd_be2 + l * 64, (float)N, acu2);
    residual_kernel<<<gridN64, B, 0, stream>>>(h, hb, u2, acu2, N * 64);
  }
  pred_kernel<<<gridN, B, 0, stream>>>(h, pred_W, pred_b, out, N);
}